// Round 14
// baseline (3651.314 us; speedup 1.0000x reference)
//
#include <hip/hip_runtime.h>
#include <hip/hip_bf16.h>

typedef __hip_bfloat16 bf16;
typedef __bf16 bf16x8 __attribute__((ext_vector_type(8)));
typedef float f32x4 __attribute__((ext_vector_type(4)));

#define AS1 __attribute__((address_space(1)))
#define AS3 __attribute__((address_space(3)))
__device__ __forceinline__ void gl_lds16(const void* g, void* l) {
    __builtin_amdgcn_global_load_lds((const AS1 void*)g, (AS3 void*)l, 16, 0, 0);
}

__device__ __forceinline__ float fexp2(float x) {
#if __has_builtin(__builtin_amdgcn_exp2f)
    return __builtin_amdgcn_exp2f(x);
#else
    return exp2f(x);
#endif
}

// XCD-chunked bijective swizzle (T1/m204). Requires nwg % 8 == 0 (all our grids satisfy).
__device__ __forceinline__ int xcd_swz(int did, int nwg) {
    return (did & 7) * (nwg >> 3) + (did >> 3);
}

// 16x32 bf16 block, XOR-swizzled (rule #21 both-sides):
//   stage:  lane l <- global row (l>>2), colchunk (l&3)^((l>>3)&3)   [coalesced 64B/4 lanes]
//   read:   lane l -> elem offset (l&15)*32 + ((l>>4) ^ (((l&15)>>1)&3))*8   [conflict-free]

// ---------------------------------------------------------------- convert f32 -> bf16 (strided rows of 768)
__global__ __launch_bounds__(256) void cvt_f32_bf16_k(const float* __restrict__ in, bf16* __restrict__ out,
                                                      int ostride, int total)
{
    int i = blockIdx.x * 256 + threadIdx.x;
    int e = i * 4;
    if (e >= total) return;
    int row = e / 768;
    int col = e - row * 768;
    const float4 f = *(const float4*)(in + e);
    bf16 o4[4];
    o4[0] = __float2bfloat16(f.x); o4[1] = __float2bfloat16(f.y);
    o4[2] = __float2bfloat16(f.z); o4[3] = __float2bfloat16(f.w);
    *(uint2*)(out + (size_t)row * ostride + col) = *(uint2*)o4;
}

// ---------------------------------------------------------------- weight transpose+convert: in[R][C] f32 -> out[C][R] bf16 (x scale)
__global__ void transpose_cvt_k(const float* __restrict__ in, bf16* __restrict__ out, int R, int C,
                                float scale, size_t lstride)
{
    __shared__ float t[32][33];
    const int tx = threadIdx.x, ty = threadIdx.y;
    in  += (size_t)blockIdx.z * R * C;
    out += (size_t)blockIdx.z * lstride;
    const int c0 = blockIdx.x * 32, r0 = blockIdx.y * 32;
    #pragma unroll
    for (int i = 0; i < 4; ++i)
        t[ty + i*8][tx] = in[(size_t)(r0 + ty + i*8) * C + c0 + tx];
    __syncthreads();
    #pragma unroll
    for (int i = 0; i < 4; ++i)
        out[(size_t)(c0 + ty + i*8) * R + r0 + tx] = __float2bfloat16(t[tx][ty + i*8] * scale);
}

// ---------------------------------------------------------------- GEMM: C[M,N] = A[M,K](lda) @ BT[N,K]^T, bf16 in, fp32 acc
// R10-proven structure: 128x128 tile, 4 waves, BK=32, XOR-swizzled fragment blocks, 3-buffer
// counted-vmcnt pipeline (distance 2, one raw barrier/iter, never vmcnt(0) mid-loop),
// cols-fastest XCD chunk (A slice L2-resident).
// EPI: 0 = bf16, 1 = bf16+ReLU, 4 = qkv-routed (q from A / k,v from A2; q->Cp, k->Ck, v->Cv transposed)
template<int EPI>
__global__ __launch_bounds__(256) void gemm_bt_k(const bf16* __restrict__ A, int lda,
                                                 const bf16* __restrict__ BT, int K,
                                                 void* __restrict__ Cp, int ldc,
                                                 bf16* __restrict__ Ck, bf16* __restrict__ Cv,
                                                 const bf16* __restrict__ A2)
{
    __shared__ bf16 a_sm[3][4096];
    __shared__ bf16 b_sm[3][4096];
    const int tid = threadIdx.x;
    const int lane = tid & 63;
    const int wid = tid >> 6;
    const int wr = wid >> 1, wc = wid & 1;

    const int nwg = gridDim.x * gridDim.y;
    const int did = blockIdx.x + gridDim.x * blockIdx.y;
    const int wgid = xcd_swz(did, nwg);
    const int col0 = (wgid % gridDim.y) * 128;   // cols fastest within XCD chunk -> A slice L2-resident
    const int row0 = (wgid / gridDim.y) * 128;
    const int g = lane >> 4, r16 = lane & 15;

    // qkv routing: tile's 128 cols lie inside one 768-segment (wave-uniform select)
    if (EPI == 4 && col0 >= 768) A = A2;     // q from A, k/v from A2

    // staging (coalesced, swizzle-inverse on source): lane l -> row l>>2, colchunk (l&3)^((l>>3)&3)
    const int r4 = lane >> 2;
    const int sc = (lane & 3) ^ ((lane >> 3) & 3);
    const bf16* gA[2]; const bf16* gB[2]; int loff[2];
    #pragma unroll
    for (int i = 0; i < 2; ++i) {
        const int blk = wid*2 + i;
        gA[i] = A  + (size_t)(row0 + blk*16 + r4) * lda + sc*8;
        gB[i] = BT + (size_t)(col0 + blk*16 + r4) * K   + sc*8;
        loff[i] = blk * 512;                 // wave-uniform LDS base; HW appends lane*16
    }
    // fragment read offset (elements) within a 512-elem block, swizzled
    const int foff = r16*32 + ((g ^ ((r16 >> 1) & 3)) * 8);

    f32x4 acc[4][4];
    #pragma unroll
    for (int m = 0; m < 4; ++m)
        #pragma unroll
        for (int n = 0; n < 4; ++n)
            #pragma unroll
            for (int r = 0; r < 4; ++r) acc[m][n][r] = 0.f;

    // prologue: stage tiles 0 and 1 (K is always >= 64 here)
    #pragma unroll
    for (int i = 0; i < 2; ++i) {
        gl_lds16(gA[i],      &a_sm[0][loff[i]]);
        gl_lds16(gB[i],      &b_sm[0][loff[i]]);
    }
    #pragma unroll
    for (int i = 0; i < 2; ++i) {
        gl_lds16(gA[i] + 32, &a_sm[1][loff[i]]);
        gl_lds16(gB[i] + 32, &b_sm[1][loff[i]]);
    }

    int cur = 0, pre = 2;
    for (int k0 = 0; k0 < K; k0 += 32) {
        // own tile-t loads done (4 newest = t+1's stay in flight); last iter: drain
        if (k0 + 32 < K) asm volatile("s_waitcnt vmcnt(4)" ::: "memory");
        else             asm volatile("s_waitcnt vmcnt(0)" ::: "memory");
        __builtin_amdgcn_s_barrier();        // all waves' t-loads landed; prev reads of slot 'pre' done
        if (k0 + 64 < K) {                   // stage t+2 into slot pre
            #pragma unroll
            for (int i = 0; i < 2; ++i) {
                gl_lds16(gA[i] + k0 + 64, &a_sm[pre][loff[i]]);
                gl_lds16(gB[i] + k0 + 64, &b_sm[pre][loff[i]]);
            }
        }
        bf16x8 af[4], bfr[4];
        #pragma unroll
        for (int m = 0; m < 4; ++m) af[m]  = *(const bf16x8*)&a_sm[cur][(wr*4 + m)*512 + foff];
        #pragma unroll
        for (int n = 0; n < 4; ++n) bfr[n] = *(const bf16x8*)&b_sm[cur][(wc*4 + n)*512 + foff];
        asm volatile("s_waitcnt lgkmcnt(0)" ::: "memory");   // frag reads complete before barrier arrival
        __builtin_amdgcn_s_setprio(1);
        #pragma unroll
        for (int m = 0; m < 4; ++m)
            #pragma unroll
            for (int n = 0; n < 4; ++n)
                acc[m][n] = __builtin_amdgcn_mfma_f32_16x16x32_bf16(af[m], bfr[n], acc[m][n], 0, 0, 0);
        __builtin_amdgcn_s_setprio(0);
        cur = (cur == 2) ? 0 : cur + 1;
        pre = (pre == 2) ? 0 : pre + 1;
    }

    #pragma unroll
    for (int m = 0; m < 4; ++m) {
        const int orow = row0 + wr*64 + m*16 + g*4;   // row = (lane>>4)*4 + reg
        #pragma unroll
        for (int n = 0; n < 4; ++n) {
            const int ocol = col0 + wc*64 + n*16 + r16;  // col = lane&15
            if (EPI == 4) {
                const int seg = ocol / 768;          // uniform per block (tile within one segment)
                const int ci = ocol - seg*768;
                if (seg <= 1) {
                    bf16* dst = (seg == 0) ? (bf16*)Cp : Ck;
                    #pragma unroll
                    for (int r = 0; r < 4; ++r)
                        dst[(size_t)(orow + r)*768 + ci] = __float2bfloat16(acc[m][n][r]);
                } else {                              // v: transposed [(n*8+h)*96+d][s]
                    const int nn = orow >> 10, ss = orow & 1023;
                    const int hh = ci / 96, dd = ci - hh * 96;
                    bf16 pk[4];
                    #pragma unroll
                    for (int r = 0; r < 4; ++r) pk[r] = __float2bfloat16(acc[m][n][r]);
                    *(uint2*)&Cv[(((size_t)nn*8 + hh)*96 + dd)*1024 + ss] = *(uint2*)pk;
                }
            } else {
                #pragma unroll
                for (int r = 0; r < 4; ++r) {
                    float v = acc[m][n][r];
                    if (EPI == 1) v = fmaxf(v, 0.f);
                    ((bf16*)Cp)[(size_t)(orow + r)*ldc + ocol] = __float2bfloat16(v);
                }
            }
        }
    }
}

// ---------------------------------------------------------------- flash attention, swapped-QK^T + defer-max
// 4 waves/block, 32 q-rows/wave (128 rows/block), grid (8, nh) -> 2x blocks vs prior (occupancy was
// grid-capped at 1 block/CU). P operand redistributed IN-REGISTER via 4-lane shfl (p_sm eliminated,
// LDS 36KB). K/V XOR-swizzled fragment blocks, 3-buffer counted-vmcnt pipeline (3 issues/wave/tile).
// Q pre-scaled by log2(e)/sqrt(96) -> exp2 domain.
__global__ __launch_bounds__(256) void attn_k(const bf16* __restrict__ qb, const bf16* __restrict__ kb,
                                              const bf16* __restrict__ vtb, bf16* __restrict__ msgb)
{
    __shared__ bf16 kv_sm[3][12*512];       // per buf: 6 K-frag blocks + 6 V-frag blocks (512 bf16 each)
    const int tid = threadIdx.x;
    const int lane = tid & 63;
    const int w = tid >> 6;                  // 4 waves
    const int g = lane >> 4, r16 = lane & 15;

    const int nwg = gridDim.x * gridDim.y;
    const int did = blockIdx.x + gridDim.x * blockIdx.y;
    const int wgid = xcd_swz(did, nwg);
    const int qx = wgid % gridDim.x;
    const int nh = wgid / gridDim.x;
    const int n = nh >> 3, h = nh & 7;
    const int q0 = qx * 128 + w * 32;

    const bf16* kbase = kb  + ((size_t)n*1024)*768 + (size_t)h*96;
    const bf16* vbase = vtb + ((size_t)(n*8 + h))*96*1024;

    // Q fragments (B-operand): 2 x 16-row groups, already scaled
    bf16x8 aq[2][3];
    #pragma unroll
    for (int qh = 0; qh < 2; ++qh) {
        const size_t qoff = ((size_t)n*1024 + q0 + qh*16 + r16) * 768 + (size_t)h*96;
        #pragma unroll
        for (int c = 0; c < 3; ++c) aq[qh][c] = *(const bf16x8*)&qb[qoff + c*32 + g*8];
    }

    // staging (coalesced, swizzle-inverse): lane l -> row l>>2, colchunk (l&3)^((l>>3)&3)
    // 12 fragment units; wave w issues units {w, w+4, w+8} (uniform 3 issues per tile)
    const int r4 = lane >> 2;
    const int sc = (lane & 3) ^ ((lane >> 3) & 3);
    const bf16* gsrc[3]; size_t gstep[3]; int dstoff[3];
    #pragma unroll
    for (int jj = 0; jj < 3; ++jj) {
        const int issue = w + jj*4;
        if (issue < 6) {
            const int c = issue >> 1, kh = issue & 1;
            gsrc[jj]  = kbase + (size_t)(kh*16 + r4)*768 + c*32 + sc*8;
            gstep[jj] = 768;
        } else {
            gsrc[jj]  = vbase + (size_t)((issue-6)*16 + r4)*1024 + sc*8;
            gstep[jj] = 1;
        }
        dstoff[jj] = issue * 512;
    }
    const int foff = r16*32 + ((g ^ ((r16 >> 1) & 3)) * 8);   // swizzled fragment read offset

    // P-redistribution source lanes (in-register transpose of the QK^T C-layout to PV A-layout):
    // lane (g,r16) holds P[q=r16][k=kh*16+g*4+r]; PV A-frag for lane g' needs k in [8g', 8g'+8)
    //  = kh-half (g'>=2) of source lanes sA = r16 + ((g'&1)<<5), sB = sA + 16.
    const int sA = r16 + ((g & 1) << 5);
    const int sB = sA + 16;
    const bool khi = (g >= 2);

    float m_run[2], l_run[2];
    #pragma unroll
    for (int qh = 0; qh < 2; ++qh) { m_run[qh] = -1e30f; l_run[qh] = 0.f; }
    f32x4 o[2][6];
    #pragma unroll
    for (int qg = 0; qg < 2; ++qg)
        #pragma unroll
        for (int f = 0; f < 6; ++f)
            #pragma unroll
            for (int r = 0; r < 4; ++r) o[qg][f][r] = 0.f;

    // prologue: stage tiles 0 and 1
    #pragma unroll
    for (int jj = 0; jj < 3; ++jj) gl_lds16(gsrc[jj], &kv_sm[0][dstoff[jj]]);
    #pragma unroll
    for (int jj = 0; jj < 3; ++jj) gl_lds16(gsrc[jj] + 32 * gstep[jj], &kv_sm[1][dstoff[jj]]);

    int cur = 0, pre = 2;
    for (int kt = 0; kt < 1024; kt += 32) {
        if (kt + 32 < 1024) asm volatile("s_waitcnt vmcnt(3)" ::: "memory");
        else                asm volatile("s_waitcnt vmcnt(0)" ::: "memory");
        __builtin_amdgcn_s_barrier();
        if (kt + 64 < 1024) {                // stage t+2 into slot pre
            #pragma unroll
            for (int jj = 0; jj < 3; ++jj)
                gl_lds16(gsrc[jj] + (size_t)(kt + 64) * gstep[jj], &kv_sm[pre][dstoff[jj]]);
        }
        const bf16* rd = kv_sm[cur];

        // QK^T swapped: s[kh][qh], C col = q (lane&15), row = k ((lane>>4)*4+reg)
        f32x4 s[2][2];
        #pragma unroll
        for (int kh = 0; kh < 2; ++kh)
            #pragma unroll
            for (int qh = 0; qh < 2; ++qh)
                #pragma unroll
                for (int r = 0; r < 4; ++r) s[kh][qh][r] = 0.f;
        __builtin_amdgcn_s_setprio(1);
        #pragma unroll
        for (int c = 0; c < 3; ++c) {
            bf16x8 ak0 = *(const bf16x8*)&rd[(c*2 + 0)*512 + foff];
            bf16x8 ak1 = *(const bf16x8*)&rd[(c*2 + 1)*512 + foff];
            s[0][0] = __builtin_amdgcn_mfma_f32_16x16x32_bf16(ak0, aq[0][c], s[0][0], 0, 0, 0);
            s[0][1] = __builtin_amdgcn_mfma_f32_16x16x32_bf16(ak0, aq[1][c], s[0][1], 0, 0, 0);
            s[1][0] = __builtin_amdgcn_mfma_f32_16x16x32_bf16(ak1, aq[0][c], s[1][0], 0, 0, 0);
            s[1][1] = __builtin_amdgcn_mfma_f32_16x16x32_bf16(ak1, aq[1][c], s[1][1], 0, 0, 0);
        }
        __builtin_amdgcn_s_setprio(0);

        // softmax, col-layout state (q = lane&15 per qh)
        float pmv[2], gr[2];
        #pragma unroll
        for (int qh = 0; qh < 2; ++qh) {
            float pm = fmaxf(fmaxf(fmaxf(s[0][qh][0], s[0][qh][1]), fmaxf(s[0][qh][2], s[0][qh][3])),
                             fmaxf(fmaxf(s[1][qh][0], s[1][qh][1]), fmaxf(s[1][qh][2], s[1][qh][3])));
            pm = fmaxf(pm, __shfl_xor(pm, 16, 64));
            pm = fmaxf(pm, __shfl_xor(pm, 32, 64));
            pmv[qh] = pm;
            gr[qh] = pm - m_run[qh];
        }
        if (__any(fmaxf(gr[0], gr[1]) > 8.0f)) {   // rare rescale (defer-max, THR=8 in log2)
            float alpha_c[2];
            #pragma unroll
            for (int qh = 0; qh < 2; ++qh) {
                float mn = fmaxf(m_run[qh], pmv[qh]);
                alpha_c[qh] = fexp2(m_run[qh] - mn);
                m_run[qh] = mn;
                l_run[qh] *= alpha_c[qh];
            }
            #pragma unroll
            for (int qg = 0; qg < 2; ++qg)
                #pragma unroll
                for (int r = 0; r < 4; ++r) {
                    float ar = __shfl(alpha_c[qg], g*4 + r, 64);   // col->row layout transpose
                    #pragma unroll
                    for (int f = 0; f < 6; ++f) o[qg][f][r] *= ar;
                }
        }
        bf16x8 pa[2];
        #pragma unroll
        for (int qh = 0; qh < 2; ++qh) {
            bf16 pk0[4], pk1[4];
            float rs = 0.f;
            #pragma unroll
            for (int r = 0; r < 4; ++r) {
                float p0 = fexp2(s[0][qh][r] - m_run[qh]);
                float p1 = fexp2(s[1][qh][r] - m_run[qh]);
                rs += p0 + p1;
                pk0[r] = __float2bfloat16(p0);
                pk1[r] = __float2bfloat16(p1);
            }
            rs += __shfl_xor(rs, 16, 64);
            rs += __shfl_xor(rs, 32, 64);
            l_run[qh] += rs;
            // in-register P redistribution: C-layout -> PV A-layout (exact)
            uint2 P0 = *(uint2*)pk0, P1 = *(uint2*)pk1;
            int a0x = __shfl((int)P0.x, sA, 64), a0y = __shfl((int)P0.y, sA, 64);
            int a1x = __shfl((int)P1.x, sA, 64), a1y = __shfl((int)P1.y, sA, 64);
            int b0x = __shfl((int)P0.x, sB, 64), b0y = __shfl((int)P0.y, sB, 64);
            int b1x = __shfl((int)P1.x, sB, 64), b1y = __shfl((int)P1.y, sB, 64);
            uint4 pau;
            pau.x = (unsigned)(khi ? a1x : a0x);
            pau.y = (unsigned)(khi ? a1y : a0y);
            pau.z = (unsigned)(khi ? b1x : b0x);
            pau.w = (unsigned)(khi ? b1y : b0y);
            pa[qh] = *(bf16x8*)&pau;
        }

        // PV: A = P rows(q), B = V^T rows(d)
        __builtin_amdgcn_s_setprio(1);
        #pragma unroll
        for (int f = 0; f < 6; ++f) {
            bf16x8 bv = *(const bf16x8*)&rd[(6 + f)*512 + foff];
            o[0][f] = __builtin_amdgcn_mfma_f32_16x16x32_bf16(pa[0], bv, o[0][f], 0, 0, 0);
            o[1][f] = __builtin_amdgcn_mfma_f32_16x16x32_bf16(pa[1], bv, o[1][f], 0, 0, 0);
        }
        __builtin_amdgcn_s_setprio(0);
        asm volatile("s_waitcnt lgkmcnt(0)" ::: "memory");   // all rd reads done before barrier arrival
        cur = (cur == 2) ? 0 : cur + 1;
        pre = (pre == 2) ? 0 : pre + 1;
    }

    // l is in col-layout; transpose via shfl for the row-layout output
    float linv[2][4];
    #pragma unroll
    for (int qg = 0; qg < 2; ++qg)
        #pragma unroll
        for (int r = 0; r < 4; ++r)
            linv[qg][r] = 1.0f / __shfl(l_run[qg], g*4 + r, 64);

    #pragma unroll
    for (int qg = 0; qg < 2; ++qg) {
        const size_t obase = ((size_t)n*1024 + q0 + qg*16 + g*4) * 768 + (size_t)h*96;
        #pragma unroll
        for (int f = 0; f < 6; ++f)
            #pragma unroll
            for (int r = 0; r < 4; ++r)
                msgb[obase + (size_t)r*768 + f*16 + r16] = __float2bfloat16(o[qg][f][r] * linv[qg][r]);
    }
}

// ---------------------------------------------------------------- LayerNorm over 768 (bf16 input)
// MODE 1: write bf16 into concat right half (stride 1536, offset 768)
// MODE 2: x += LN(in); also write bf16 of new x into concat left half (stride 1536, offset 0)
template<int MODE>
__global__ __launch_bounds__(256) void ln_k(const bf16* __restrict__ in, const float* __restrict__ g,
                                            const float* __restrict__ b, bf16* __restrict__ outc,
                                            float* __restrict__ x)
{
    const int row = blockIdx.x;
    const int tid = threadIdx.x;
    const bf16* rp = in + (size_t)row * 768;
    float v[3];
    #pragma unroll
    for (int j = 0; j < 3; ++j) v[j] = __bfloat162float(rp[tid + j*256]);
    float s  = v[0] + v[1] + v[2];
    float sq = v[0]*v[0] + v[1]*v[1] + v[2]*v[2];
    #pragma unroll
    for (int off = 32; off >= 1; off >>= 1) {
        s  += __shfl_xor(s,  off, 64);
        sq += __shfl_xor(sq, off, 64);
    }
    __shared__ float red[2][4];
    const int wid = tid >> 6;
    if ((tid & 63) == 0) { red[0][wid] = s; red[1][wid] = sq; }
    __syncthreads();
    const float S  = red[0][0] + red[0][1] + red[0][2] + red[0][3];
    const float SQ = red[1][0] + red[1][1] + red[1][2] + red[1][3];
    const float mu = S * (1.f/768.f);
    float var = SQ * (1.f/768.f) - mu*mu;
    var = fmaxf(var, 0.f);
    const float rs = rsqrtf(var + 1e-5f);
    #pragma unroll
    for (int j = 0; j < 3; ++j) {
        const int c = tid + j*256;
        const float y = (v[j] - mu) * rs * g[c] + b[c];
        if (MODE == 1) {
            outc[(size_t)row*1536 + 768 + c] = __float2bfloat16(y);
        } else {
            const float nx = x[(size_t)row*768 + c] + y;
            x[(size_t)row*768 + c] = nx;
            outc[(size_t)row*1536 + c] = __float2bfloat16(nx);
        }
    }
}

// ---------------------------------------------------------------- host
extern "C" void kernel_launch(void* const* d_in, const int* in_sizes, int n_in,
                              void* d_out, int out_size, void* d_ws, size_t ws_size,
                              hipStream_t stream)
{
    const float* feat0 = (const float*)d_in[0];
    const float* feat1 = (const float*)d_in[1];
    const float* Wq = (const float*)d_in[2];
    const float* Wk = (const float*)d_in[3];
    const float* Wv = (const float*)d_in[4];
    const float* Wm = (const float*)d_in[5];
    const float* W1 = (const float*)d_in[6];
    const float* W2 = (const float*)d_in[7];
    const float* g1 = (const float*)d_in[8];
    const float* b1 = (const float*)d_in[9];
    const float* g2 = (const float*)d_in[10];
    const float* b2 = (const float*)d_in[11];

    // workspace plan; RB = row capacity of activation buffers (16384 if batched self layers fit)
    bf16 *wqkvT, *wmT, *w1T, *w2T, *concat0, *concat1, *qb, *kb, *vtb, *m1b, *t0b;
    auto plan = [&](int RB) -> size_t {
        char* p = (char*)d_ws;
        auto take = [&](size_t bytes) { char* q = p; p += (bytes + 255) & ~(size_t)255; return q; };
        wqkvT = (bf16*)take((size_t)8*2304*768*2);
        wmT  = (bf16*)take((size_t)8*768*768*2);
        w1T  = (bf16*)take((size_t)8*1536*1536*2);
        w2T  = (bf16*)take((size_t)8*768*1536*2);
        concat0 = (bf16*)take((size_t)8192*1536*2);   // concat1 must follow contiguously
        concat1 = (bf16*)take((size_t)8192*1536*2);
        qb   = (bf16*)take((size_t)RB*768*2);
        kb   = (bf16*)take((size_t)RB*768*2);
        vtb  = (bf16*)take((size_t)RB*768*2);
        m1b  = (bf16*)take((size_t)RB*1536*2);
        t0b  = (bf16*)take((size_t)RB*768*2);
        return (size_t)(p - (char*)d_ws);
    };
    bool batched = plan(16384) <= ws_size;
    if (!batched) plan(8192);
    bf16* msgb = qb;  // alias: attn reads its Q region before writing msg; regions per block coincide

    float* x0 = (float*)d_out;
    float* x1 = x0 + (size_t)8192*768;

    hipMemcpyAsync(x0, feat0, (size_t)8192*768*4, hipMemcpyDeviceToDevice, stream);
    hipMemcpyAsync(x1, feat1, (size_t)8192*768*4, hipMemcpyDeviceToDevice, stream);

    const float s_qk = 0.14724444f;  // log2(e)/sqrt(96), folded into Wq -> QK^T lands in exp2 domain
    const dim3 tb(32, 8);
    const size_t QKV = (size_t)2304*768;
    transpose_cvt_k<<<dim3(24,24,8), tb, 0, stream>>>(Wq, wqkvT,            768, 768,  s_qk, QKV);
    transpose_cvt_k<<<dim3(24,24,8), tb, 0, stream>>>(Wk, wqkvT + 768*768,  768, 768,  1.0f, QKV);
    transpose_cvt_k<<<dim3(24,24,8), tb, 0, stream>>>(Wv, wqkvT + 1536*768, 768, 768,  1.0f, QKV);
    transpose_cvt_k<<<dim3(24,24,8), tb, 0, stream>>>(Wm, wmT, 768, 768,  1.0f, (size_t)768*768);
    transpose_cvt_k<<<dim3(48,48,8), tb, 0, stream>>>(W1, w1T, 1536, 1536, 1.0f, (size_t)1536*1536);
    transpose_cvt_k<<<dim3(24,48,8), tb, 0, stream>>>(W2, w2T, 1536, 768,  1.0f, (size_t)1536*768);

    const int total = 8192*768;
    cvt_f32_bf16_k<<<6144, 256, 0, stream>>>(feat0, concat0, 1536, total);
    cvt_f32_bf16_k<<<6144, 256, 0, stream>>>(feat1, concat1, 1536, total);

    // one encoder layer over M rows (M = 8192, or 16384 for batched self pairs)
    // qkv in ONE launch: q-segment reads cS, k/v-segments read cR (self: cR == cS)
    auto encode = [&](float* x, bf16* cS, const bf16* cR, int i, int M) {
        const bf16* wl = wqkvT + (size_t)i * QKV;
        const int MT = M / 128;
        gemm_bt_k<4><<<dim3(MT,18), 256, 0, stream>>>(cS, 1536, wl, 768, qb, 768, kb, vtb, cR);
        attn_k<<<dim3(8, (M/1024)*8), 256, 0, stream>>>(qb, kb, vtb, msgb);
        gemm_bt_k<0><<<dim3(MT,6),  256, 0, stream>>>(msgb, 768, wmT + (size_t)i*768*768, 768,
                                                      t0b, 768, nullptr, nullptr, nullptr);
        ln_k<1><<<M, 256, 0, stream>>>(t0b, g1 + i*768, b1 + i*768, cS, nullptr);
        gemm_bt_k<1><<<dim3(MT,12), 256, 0, stream>>>(cS, 1536, w1T + (size_t)i*1536*1536, 1536,
                                                      m1b, 1536, nullptr, nullptr, nullptr);
        gemm_bt_k<0><<<dim3(MT,6),  256, 0, stream>>>(m1b, 1536, w2T + (size_t)i*768*1536, 1536,
                                                      t0b, 768, nullptr, nullptr, nullptr);
        ln_k<2><<<M, 256, 0, stream>>>(t0b, g2 + i*768, b2 + i*768, cS, x);
    };

    for (int i = 0; i < 8; ++i) {
        if ((i & 1) == 0) {
            if (batched) {
                // feat0/feat1 self layers are independent; x0|x1 and concat0|concat1 are contiguous
                encode(x0, concat0, concat0, i, 16384);
            } else {
                encode(x0, concat0, concat0, i, 8192);
                encode(x1, concat1, concat1, i, 8192);
            }
        } else {
            encode(x0, concat0, concat1, i, 8192);
            encode(x1, concat1, concat0, i, 8192);
        }
    }
}

// Round 15
// 3386.725 us; speedup vs baseline: 1.0781x; 1.0781x over previous
//
#include <hip/hip_runtime.h>
#include <hip/hip_bf16.h>

typedef __hip_bfloat16 bf16;
typedef __bf16 bf16x8 __attribute__((ext_vector_type(8)));
typedef float f32x4 __attribute__((ext_vector_type(4)));

#define AS1 __attribute__((address_space(1)))
#define AS3 __attribute__((address_space(3)))
__device__ __forceinline__ void gl_lds16(const void* g, void* l) {
    __builtin_amdgcn_global_load_lds((const AS1 void*)g, (AS3 void*)l, 16, 0, 0);
}

__device__ __forceinline__ float fexp2(float x) {
#if __has_builtin(__builtin_amdgcn_exp2f)
    return __builtin_amdgcn_exp2f(x);
#else
    return exp2f(x);
#endif
}

// XCD-chunked bijective swizzle (T1/m204). Requires nwg % 8 == 0 (all our grids satisfy).
__device__ __forceinline__ int xcd_swz(int did, int nwg) {
    return (did & 7) * (nwg >> 3) + (did >> 3);
}

// 16x32 bf16 block, XOR-swizzled (rule #21 both-sides):
//   stage:  lane l <- global row (l>>2), colchunk (l&3)^((l>>3)&3)   [coalesced 64B/4 lanes]
//   read:   lane l -> elem offset (l&15)*32 + ((l>>4) ^ (((l&15)>>1)&3))*8   [conflict-free]

// ---------------------------------------------------------------- convert f32 -> bf16 (strided rows of 768)
// also optionally copies the fp32 input into xout (fuses the initial residual-stream memcpy)
__global__ __launch_bounds__(256) void cvt_f32_bf16_k(const float* __restrict__ in, bf16* __restrict__ out,
                                                      int ostride, int total, float* __restrict__ xout)
{
    int i = blockIdx.x * 256 + threadIdx.x;
    int e = i * 4;
    if (e >= total) return;
    int row = e / 768;
    int col = e - row * 768;
    const float4 f = *(const float4*)(in + e);
    bf16 o4[4];
    o4[0] = __float2bfloat16(f.x); o4[1] = __float2bfloat16(f.y);
    o4[2] = __float2bfloat16(f.z); o4[3] = __float2bfloat16(f.w);
    *(uint2*)(out + (size_t)row * ostride + col) = *(uint2*)o4;
    if (xout) *(float4*)(xout + e) = f;
}

// ---------------------------------------------------------------- weight transpose+convert: in[R][C] f32 -> out[C][R] bf16 (x scale)
__global__ void transpose_cvt_k(const float* __restrict__ in, bf16* __restrict__ out, int R, int C,
                                float scale, size_t lstride)
{
    __shared__ float t[32][33];
    const int tx = threadIdx.x, ty = threadIdx.y;
    in  += (size_t)blockIdx.z * R * C;
    out += (size_t)blockIdx.z * lstride;
    const int c0 = blockIdx.x * 32, r0 = blockIdx.y * 32;
    #pragma unroll
    for (int i = 0; i < 4; ++i)
        t[ty + i*8][tx] = in[(size_t)(r0 + ty + i*8) * C + c0 + tx];
    __syncthreads();
    #pragma unroll
    for (int i = 0; i < 4; ++i)
        out[(size_t)(c0 + ty + i*8) * R + r0 + tx] = __float2bfloat16(t[tx][ty + i*8] * scale);
}

// ---------------------------------------------------------------- GEMM: C[M,N] = A[M,K](lda) @ BT[N,K]^T, bf16 in, fp32 acc
// R10-proven structure: 128x128 tile, 4 waves, BK=32, XOR-swizzled fragment blocks, 3-buffer
// counted-vmcnt pipeline (distance 2, one raw barrier/iter, never vmcnt(0) mid-loop),
// cols-fastest XCD chunk (A slice L2-resident).
// EPI: 0 = bf16, 1 = bf16+ReLU, 4 = qkv-routed (q from A / k,v from A2; q->Cp, k->Ck, v->Cv transposed)
template<int EPI>
__global__ __launch_bounds__(256) void gemm_bt_k(const bf16* __restrict__ A, int lda,
                                                 const bf16* __restrict__ BT, int K,
                                                 void* __restrict__ Cp, int ldc,
                                                 bf16* __restrict__ Ck, bf16* __restrict__ Cv,
                                                 const bf16* __restrict__ A2)
{
    __shared__ bf16 a_sm[3][4096];
    __shared__ bf16 b_sm[3][4096];
    const int tid = threadIdx.x;
    const int lane = tid & 63;
    const int wid = tid >> 6;
    const int wr = wid >> 1, wc = wid & 1;

    const int nwg = gridDim.x * gridDim.y;
    const int did = blockIdx.x + gridDim.x * blockIdx.y;
    const int wgid = xcd_swz(did, nwg);
    const int col0 = (wgid % gridDim.y) * 128;   // cols fastest within XCD chunk -> A slice L2-resident
    const int row0 = (wgid / gridDim.y) * 128;
    const int g = lane >> 4, r16 = lane & 15;

    // qkv routing: tile's 128 cols lie inside one 768-segment (wave-uniform select)
    if (EPI == 4 && col0 >= 768) A = A2;     // q from A, k/v from A2

    // staging (coalesced, swizzle-inverse on source): lane l -> row l>>2, colchunk (l&3)^((l>>3)&3)
    const int r4 = lane >> 2;
    const int sc = (lane & 3) ^ ((lane >> 3) & 3);
    const bf16* gA[2]; const bf16* gB[2]; int loff[2];
    #pragma unroll
    for (int i = 0; i < 2; ++i) {
        const int blk = wid*2 + i;
        gA[i] = A  + (size_t)(row0 + blk*16 + r4) * lda + sc*8;
        gB[i] = BT + (size_t)(col0 + blk*16 + r4) * K   + sc*8;
        loff[i] = blk * 512;                 // wave-uniform LDS base; HW appends lane*16
    }
    // fragment read offset (elements) within a 512-elem block, swizzled
    const int foff = r16*32 + ((g ^ ((r16 >> 1) & 3)) * 8);

    f32x4 acc[4][4];
    #pragma unroll
    for (int m = 0; m < 4; ++m)
        #pragma unroll
        for (int n = 0; n < 4; ++n)
            #pragma unroll
            for (int r = 0; r < 4; ++r) acc[m][n][r] = 0.f;

    // prologue: stage tiles 0 and 1 (K is always >= 64 here)
    #pragma unroll
    for (int i = 0; i < 2; ++i) {
        gl_lds16(gA[i],      &a_sm[0][loff[i]]);
        gl_lds16(gB[i],      &b_sm[0][loff[i]]);
    }
    #pragma unroll
    for (int i = 0; i < 2; ++i) {
        gl_lds16(gA[i] + 32, &a_sm[1][loff[i]]);
        gl_lds16(gB[i] + 32, &b_sm[1][loff[i]]);
    }

    int cur = 0, pre = 2;
    for (int k0 = 0; k0 < K; k0 += 32) {
        // own tile-t loads done (4 newest = t+1's stay in flight); last iter: drain
        if (k0 + 32 < K) asm volatile("s_waitcnt vmcnt(4)" ::: "memory");
        else             asm volatile("s_waitcnt vmcnt(0)" ::: "memory");
        __builtin_amdgcn_s_barrier();        // all waves' t-loads landed; prev reads of slot 'pre' done
        if (k0 + 64 < K) {                   // stage t+2 into slot pre
            #pragma unroll
            for (int i = 0; i < 2; ++i) {
                gl_lds16(gA[i] + k0 + 64, &a_sm[pre][loff[i]]);
                gl_lds16(gB[i] + k0 + 64, &b_sm[pre][loff[i]]);
            }
        }
        bf16x8 af[4], bfr[4];
        #pragma unroll
        for (int m = 0; m < 4; ++m) af[m]  = *(const bf16x8*)&a_sm[cur][(wr*4 + m)*512 + foff];
        #pragma unroll
        for (int n = 0; n < 4; ++n) bfr[n] = *(const bf16x8*)&b_sm[cur][(wc*4 + n)*512 + foff];
        asm volatile("s_waitcnt lgkmcnt(0)" ::: "memory");   // frag reads complete before barrier arrival
        __builtin_amdgcn_s_setprio(1);
        #pragma unroll
        for (int m = 0; m < 4; ++m)
            #pragma unroll
            for (int n = 0; n < 4; ++n)
                acc[m][n] = __builtin_amdgcn_mfma_f32_16x16x32_bf16(af[m], bfr[n], acc[m][n], 0, 0, 0);
        __builtin_amdgcn_s_setprio(0);
        cur = (cur == 2) ? 0 : cur + 1;
        pre = (pre == 2) ? 0 : pre + 1;
    }

    #pragma unroll
    for (int m = 0; m < 4; ++m) {
        const int orow = row0 + wr*64 + m*16 + g*4;   // row = (lane>>4)*4 + reg
        #pragma unroll
        for (int n = 0; n < 4; ++n) {
            const int ocol = col0 + wc*64 + n*16 + r16;  // col = lane&15
            if (EPI == 4) {
                const int seg = ocol / 768;          // uniform per block (tile within one segment)
                const int ci = ocol - seg*768;
                if (seg <= 1) {
                    bf16* dst = (seg == 0) ? (bf16*)Cp : Ck;
                    #pragma unroll
                    for (int r = 0; r < 4; ++r)
                        dst[(size_t)(orow + r)*768 + ci] = __float2bfloat16(acc[m][n][r]);
                } else {                              // v: transposed [(n*8+h)*96+d][s]
                    const int nn = orow >> 10, ss = orow & 1023;
                    const int hh = ci / 96, dd = ci - hh * 96;
                    bf16 pk[4];
                    #pragma unroll
                    for (int r = 0; r < 4; ++r) pk[r] = __float2bfloat16(acc[m][n][r]);
                    *(uint2*)&Cv[(((size_t)nn*8 + hh)*96 + dd)*1024 + ss] = *(uint2*)pk;
                }
            } else {
                #pragma unroll
                for (int r = 0; r < 4; ++r) {
                    float v = acc[m][n][r];
                    if (EPI == 1) v = fmaxf(v, 0.f);
                    ((bf16*)Cp)[(size_t)(orow + r)*ldc + ocol] = __float2bfloat16(v);
                }
            }
        }
    }
}

// ---------------------------------------------------------------- flash attention, swapped-QK^T + defer-max
// 8 waves/block, 32 q-rows/wave. K/V XOR-swizzled fragment blocks, 3-buffer counted-vmcnt pipeline
// (distance 2, one raw barrier/iter). Q pre-scaled by log2(e)/sqrt(96) -> exp2 domain.
__global__ __launch_bounds__(512) void attn_k(const bf16* __restrict__ qb, const bf16* __restrict__ kb,
                                              const bf16* __restrict__ vtb, bf16* __restrict__ msgb)
{
    __shared__ bf16 kv_sm[3][12*512];       // per buf: 6 K-frag blocks + 6 V-frag blocks (512 bf16 each)
    __shared__ bf16 p_sm_all[8][32][40];
    const int tid = threadIdx.x;
    const int lane = tid & 63;
    const int w = tid >> 6;
    const int g = lane >> 4, r16 = lane & 15;

    const int nwg = gridDim.x * gridDim.y;
    const int did = blockIdx.x + gridDim.x * blockIdx.y;
    const int wgid = xcd_swz(did, nwg);
    const int qx = wgid % gridDim.x;
    const int nh = wgid / gridDim.x;
    const int n = nh >> 3, h = nh & 7;
    const int q0 = qx * 256 + w * 32;

    bf16 (*p_sm)[40] = p_sm_all[w];

    const bf16* kbase = kb  + ((size_t)n*1024)*768 + (size_t)h*96;
    const bf16* vbase = vtb + ((size_t)(n*8 + h))*96*1024;

    // Q fragments (B-operand): 2 x 16-row groups, already scaled
    bf16x8 aq[2][3];
    #pragma unroll
    for (int qh = 0; qh < 2; ++qh) {
        const size_t qoff = ((size_t)n*1024 + q0 + qh*16 + r16) * 768 + (size_t)h*96;
        #pragma unroll
        for (int c = 0; c < 3; ++c) aq[qh][c] = *(const bf16x8*)&qb[qoff + c*32 + g*8];
    }

    // staging (coalesced, swizzle-inverse): lane l -> row l>>2, colchunk (l&3)^((l>>3)&3)
    const int r4 = lane >> 2;
    const int sc = (lane & 3) ^ ((lane >> 3) & 3);
    const bf16* gsrc[2]; size_t gstep[2]; int dstoff[2];
    const int nissue = (w < 4) ? 2 : 1;
    #pragma unroll
    for (int jj = 0; jj < 2; ++jj) {
        const int issue = w + jj*8;
        if (issue < 6) {
            const int c = issue >> 1, kh = issue & 1;
            gsrc[jj]  = kbase + (size_t)(kh*16 + r4)*768 + c*32 + sc*8;
            gstep[jj] = 768;
        } else {
            gsrc[jj]  = vbase + (size_t)((issue-6)*16 + r4)*1024 + sc*8;
            gstep[jj] = 1;
        }
        dstoff[jj] = (issue < 12) ? issue * 512 : 0;
    }
    const int foff = r16*32 + ((g ^ ((r16 >> 1) & 3)) * 8);   // swizzled fragment read offset

    float m_run[2], l_run[2];
    #pragma unroll
    for (int qh = 0; qh < 2; ++qh) { m_run[qh] = -1e30f; l_run[qh] = 0.f; }
    f32x4 o[2][6];
    #pragma unroll
    for (int qg = 0; qg < 2; ++qg)
        #pragma unroll
        for (int f = 0; f < 6; ++f)
            #pragma unroll
            for (int r = 0; r < 4; ++r) o[qg][f][r] = 0.f;

    // prologue: stage tiles 0 and 1
    gl_lds16(gsrc[0], &kv_sm[0][dstoff[0]]);
    if (nissue == 2) gl_lds16(gsrc[1], &kv_sm[0][dstoff[1]]);
    gl_lds16(gsrc[0] + 32 * gstep[0], &kv_sm[1][dstoff[0]]);
    if (nissue == 2) gl_lds16(gsrc[1] + 32 * gstep[1], &kv_sm[1][dstoff[1]]);

    int cur = 0, pre = 2;
    for (int kt = 0; kt < 1024; kt += 32) {
        if (kt + 32 < 1024) {
            if (nissue == 2) asm volatile("s_waitcnt vmcnt(2)" ::: "memory");
            else             asm volatile("s_waitcnt vmcnt(1)" ::: "memory");
        } else {
            asm volatile("s_waitcnt vmcnt(0)" ::: "memory");
        }
        __builtin_amdgcn_s_barrier();
        if (kt + 64 < 1024) {                // stage t+2 into slot pre
            gl_lds16(gsrc[0] + (size_t)(kt + 64) * gstep[0], &kv_sm[pre][dstoff[0]]);
            if (nissue == 2) gl_lds16(gsrc[1] + (size_t)(kt + 64) * gstep[1], &kv_sm[pre][dstoff[1]]);
        }
        const bf16* rd = kv_sm[cur];

        // QK^T swapped: s[kh][qh], C col = q (lane&15), row = k ((lane>>4)*4+reg)
        f32x4 s[2][2];
        #pragma unroll
        for (int kh = 0; kh < 2; ++kh)
            #pragma unroll
            for (int qh = 0; qh < 2; ++qh)
                #pragma unroll
                for (int r = 0; r < 4; ++r) s[kh][qh][r] = 0.f;
        __builtin_amdgcn_s_setprio(1);
        #pragma unroll
        for (int c = 0; c < 3; ++c) {
            bf16x8 ak0 = *(const bf16x8*)&rd[(c*2 + 0)*512 + foff];
            bf16x8 ak1 = *(const bf16x8*)&rd[(c*2 + 1)*512 + foff];
            s[0][0] = __builtin_amdgcn_mfma_f32_16x16x32_bf16(ak0, aq[0][c], s[0][0], 0, 0, 0);
            s[0][1] = __builtin_amdgcn_mfma_f32_16x16x32_bf16(ak0, aq[1][c], s[0][1], 0, 0, 0);
            s[1][0] = __builtin_amdgcn_mfma_f32_16x16x32_bf16(ak1, aq[0][c], s[1][0], 0, 0, 0);
            s[1][1] = __builtin_amdgcn_mfma_f32_16x16x32_bf16(ak1, aq[1][c], s[1][1], 0, 0, 0);
        }
        __builtin_amdgcn_s_setprio(0);

        // softmax, col-layout state (q = lane&15 per qh)
        float pmv[2], gr[2];
        #pragma unroll
        for (int qh = 0; qh < 2; ++qh) {
            float pm = fmaxf(fmaxf(fmaxf(s[0][qh][0], s[0][qh][1]), fmaxf(s[0][qh][2], s[0][qh][3])),
                             fmaxf(fmaxf(s[1][qh][0], s[1][qh][1]), fmaxf(s[1][qh][2], s[1][qh][3])));
            pm = fmaxf(pm, __shfl_xor(pm, 16, 64));
            pm = fmaxf(pm, __shfl_xor(pm, 32, 64));
            pmv[qh] = pm;
            gr[qh] = pm - m_run[qh];
        }
        if (__any(fmaxf(gr[0], gr[1]) > 8.0f)) {   // rare rescale (defer-max, THR=8 in log2)
            float alpha_c[2];
            #pragma unroll
            for (int qh = 0; qh < 2; ++qh) {
                float mn = fmaxf(m_run[qh], pmv[qh]);
                alpha_c[qh] = fexp2(m_run[qh] - mn);
                m_run[qh] = mn;
                l_run[qh] *= alpha_c[qh];
            }
            #pragma unroll
            for (int qg = 0; qg < 2; ++qg)
                #pragma unroll
                for (int r = 0; r < 4; ++r) {
                    float ar = __shfl(alpha_c[qg], g*4 + r, 64);   // col->row layout transpose
                    #pragma unroll
                    for (int f = 0; f < 6; ++f) o[qg][f][r] *= ar;
                }
        }
        #pragma unroll
        for (int qh = 0; qh < 2; ++qh) {
            bf16 pk0[4], pk1[4];
            float rs = 0.f;
            #pragma unroll
            for (int r = 0; r < 4; ++r) {
                float p0 = fexp2(s[0][qh][r] - m_run[qh]);
                float p1 = fexp2(s[1][qh][r] - m_run[qh]);
                rs += p0 + p1;
                pk0[r] = __float2bfloat16(p0);
                pk1[r] = __float2bfloat16(p1);
            }
            rs += __shfl_xor(rs, 16, 64);
            rs += __shfl_xor(rs, 32, 64);
            l_run[qh] += rs;
            *(uint2*)&p_sm[qh*16 + r16][g*4]      = *(uint2*)pk0;   // P[q][k], 4 k per 8B write
            *(uint2*)&p_sm[qh*16 + r16][16 + g*4] = *(uint2*)pk1;
        }

        // PV: A = P rows(q), B = V^T rows(d)
        bf16x8 pa0 = *(const bf16x8*)&p_sm[r16][g*8];
        bf16x8 pa1 = *(const bf16x8*)&p_sm[16 + r16][g*8];
        __builtin_amdgcn_s_setprio(1);
        #pragma unroll
        for (int f = 0; f < 6; ++f) {
            bf16x8 bv = *(const bf16x8*)&rd[(6 + f)*512 + foff];
            o[0][f] = __builtin_amdgcn_mfma_f32_16x16x32_bf16(pa0, bv, o[0][f], 0, 0, 0);
            o[1][f] = __builtin_amdgcn_mfma_f32_16x16x32_bf16(pa1, bv, o[1][f], 0, 0, 0);
        }
        __builtin_amdgcn_s_setprio(0);
        asm volatile("s_waitcnt lgkmcnt(0)" ::: "memory");   // all rd/p_sm reads done before barrier arrival
        cur = (cur == 2) ? 0 : cur + 1;
        pre = (pre == 2) ? 0 : pre + 1;
    }

    // l is in col-layout; transpose via shfl for the row-layout output
    float linv[2][4];
    #pragma unroll
    for (int qg = 0; qg < 2; ++qg)
        #pragma unroll
        for (int r = 0; r < 4; ++r)
            linv[qg][r] = 1.0f / __shfl(l_run[qg], g*4 + r, 64);

    #pragma unroll
    for (int qg = 0; qg < 2; ++qg) {
        const size_t obase = ((size_t)n*1024 + q0 + qg*16 + g*4) * 768 + (size_t)h*96;
        #pragma unroll
        for (int f = 0; f < 6; ++f)
            #pragma unroll
            for (int r = 0; r < 4; ++r)
                msgb[obase + (size_t)r*768 + f*16 + r16] = __float2bfloat16(o[qg][f][r] * linv[qg][r]);
    }
}

// ---------------------------------------------------------------- LayerNorm over 768 (bf16 input)
// MODE 1: write bf16 into concat right half (stride 1536, offset 768)
// MODE 2: x += LN(in); also write bf16 of new x into concat left half (stride 1536, offset 0)
template<int MODE>
__global__ __launch_bounds__(256) void ln_k(const bf16* __restrict__ in, const float* __restrict__ g,
                                            const float* __restrict__ b, bf16* __restrict__ outc,
                                            float* __restrict__ x)
{
    const int row = blockIdx.x;
    const int tid = threadIdx.x;
    const bf16* rp = in + (size_t)row * 768;
    float v[3];
    #pragma unroll
    for (int j = 0; j < 3; ++j) v[j] = __bfloat162float(rp[tid + j*256]);
    float s  = v[0] + v[1] + v[2];
    float sq = v[0]*v[0] + v[1]*v[1] + v[2]*v[2];
    #pragma unroll
    for (int off = 32; off >= 1; off >>= 1) {
        s  += __shfl_xor(s,  off, 64);
        sq += __shfl_xor(sq, off, 64);
    }
    __shared__ float red[2][4];
    const int wid = tid >> 6;
    if ((tid & 63) == 0) { red[0][wid] = s; red[1][wid] = sq; }
    __syncthreads();
    const float S  = red[0][0] + red[0][1] + red[0][2] + red[0][3];
    const float SQ = red[1][0] + red[1][1] + red[1][2] + red[1][3];
    const float mu = S * (1.f/768.f);
    float var = SQ * (1.f/768.f) - mu*mu;
    var = fmaxf(var, 0.f);
    const float rs = rsqrtf(var + 1e-5f);
    #pragma unroll
    for (int j = 0; j < 3; ++j) {
        const int c = tid + j*256;
        const float y = (v[j] - mu) * rs * g[c] + b[c];
        if (MODE == 1) {
            outc[(size_t)row*1536 + 768 + c] = __float2bfloat16(y);
        } else {
            const float nx = x[(size_t)row*768 + c] + y;
            x[(size_t)row*768 + c] = nx;
            outc[(size_t)row*1536 + c] = __float2bfloat16(nx);
        }
    }
}

// ---------------------------------------------------------------- host
extern "C" void kernel_launch(void* const* d_in, const int* in_sizes, int n_in,
                              void* d_out, int out_size, void* d_ws, size_t ws_size,
                              hipStream_t stream)
{
    const float* feat0 = (const float*)d_in[0];
    const float* feat1 = (const float*)d_in[1];
    const float* Wq = (const float*)d_in[2];
    const float* Wk = (const float*)d_in[3];
    const float* Wv = (const float*)d_in[4];
    const float* Wm = (const float*)d_in[5];
    const float* W1 = (const float*)d_in[6];
    const float* W2 = (const float*)d_in[7];
    const float* g1 = (const float*)d_in[8];
    const float* b1 = (const float*)d_in[9];
    const float* g2 = (const float*)d_in[10];
    const float* b2 = (const float*)d_in[11];

    // workspace plan; RB = row capacity of activation buffers (16384 if batched self layers fit)
    bf16 *wqkvT, *wmT, *w1T, *w2T, *concat0, *concat1, *qb, *kb, *vtb, *m1b, *t0b;
    auto plan = [&](int RB) -> size_t {
        char* p = (char*)d_ws;
        auto take = [&](size_t bytes) { char* q = p; p += (bytes + 255) & ~(size_t)255; return q; };
        wqkvT = (bf16*)take((size_t)8*2304*768*2);
        wmT  = (bf16*)take((size_t)8*768*768*2);
        w1T  = (bf16*)take((size_t)8*1536*1536*2);
        w2T  = (bf16*)take((size_t)8*768*1536*2);
        concat0 = (bf16*)take((size_t)8192*1536*2);   // concat1 must follow contiguously
        concat1 = (bf16*)take((size_t)8192*1536*2);
        qb   = (bf16*)take((size_t)RB*768*2);
        kb   = (bf16*)take((size_t)RB*768*2);
        vtb  = (bf16*)take((size_t)RB*768*2);
        m1b  = (bf16*)take((size_t)RB*1536*2);
        t0b  = (bf16*)take((size_t)RB*768*2);
        return (size_t)(p - (char*)d_ws);
    };
    bool batched = plan(16384) <= ws_size;
    if (!batched) plan(8192);
    bf16* msgb = qb;  // alias: attn reads its Q region before writing msg; regions per block coincide

    float* x0 = (float*)d_out;
    float* x1 = x0 + (size_t)8192*768;

    const float s_qk = 0.14724444f;  // log2(e)/sqrt(96), folded into Wq -> QK^T lands in exp2 domain
    const dim3 tb(32, 8);
    const size_t QKV = (size_t)2304*768;
    transpose_cvt_k<<<dim3(24,24,8), tb, 0, stream>>>(Wq, wqkvT,            768, 768,  s_qk, QKV);
    transpose_cvt_k<<<dim3(24,24,8), tb, 0, stream>>>(Wk, wqkvT + 768*768,  768, 768,  1.0f, QKV);
    transpose_cvt_k<<<dim3(24,24,8), tb, 0, stream>>>(Wv, wqkvT + 1536*768, 768, 768,  1.0f, QKV);
    transpose_cvt_k<<<dim3(24,24,8), tb, 0, stream>>>(Wm, wmT, 768, 768,  1.0f, (size_t)768*768);
    transpose_cvt_k<<<dim3(48,48,8), tb, 0, stream>>>(W1, w1T, 1536, 1536, 1.0f, (size_t)1536*1536);
    transpose_cvt_k<<<dim3(24,48,8), tb, 0, stream>>>(W2, w2T, 1536, 768,  1.0f, (size_t)1536*768);

    const int total = 8192*768;
    // fused: bf16 concat-left write + fp32 residual-stream init (replaces 2x hipMemcpyAsync)
    cvt_f32_bf16_k<<<6144, 256, 0, stream>>>(feat0, concat0, 1536, total, x0);
    cvt_f32_bf16_k<<<6144, 256, 0, stream>>>(feat1, concat1, 1536, total, x1);

    // one encoder layer over M rows (M = 8192, or 16384 for batched self pairs)
    // qkv in ONE launch: q-segment reads cS, k/v-segments read cR (self: cR == cS)
    auto encode = [&](float* x, bf16* cS, const bf16* cR, int i, int M) {
        const bf16* wl = wqkvT + (size_t)i * QKV;
        const int MT = M / 128;
        gemm_bt_k<4><<<dim3(MT,18), 256, 0, stream>>>(cS, 1536, wl, 768, qb, 768, kb, vtb, cR);
        attn_k<<<dim3(4, (M/1024)*8), 512, 0, stream>>>(qb, kb, vtb, msgb);
        gemm_bt_k<0><<<dim3(MT,6),  256, 0, stream>>>(msgb, 768, wmT + (size_t)i*768*768, 768,
                                                      t0b, 768, nullptr, nullptr, nullptr);
        ln_k<1><<<M, 256, 0, stream>>>(t0b, g1 + i*768, b1 + i*768, cS, nullptr);
        gemm_bt_k<1><<<dim3(MT,12), 256, 0, stream>>>(cS, 1536, w1T + (size_t)i*1536*1536, 1536,
                                                      m1b, 1536, nullptr, nullptr, nullptr);
        gemm_bt_k<0><<<dim3(MT,6),  256, 0, stream>>>(m1b, 1536, w2T + (size_t)i*768*1536, 1536,
                                                      t0b, 768, nullptr, nullptr, nullptr);
        ln_k<2><<<M, 256, 0, stream>>>(t0b, g2 + i*768, b2 + i*768, cS, x);
    };

    for (int i = 0; i < 8; ++i) {
        if ((i & 1) == 0) {
            if (batched) {
                // feat0/feat1 self layers are independent; x0|x1 and concat0|concat1 are contiguous
                encode(x0, concat0, concat0, i, 16384);
            } else {
                encode(x0, concat0, concat0, i, 8192);
                encode(x1, concat1, concat1, i, 8192);
            }
        } else {
            encode(x0, concat0, concat1, i, 8192);
            encode(x1, concat1, concat0, i, 8192);
        }
    }
}

// Round 17
// 3351.562 us; speedup vs baseline: 1.0894x; 1.0105x over previous
//
#include <hip/hip_runtime.h>
#include <hip/hip_bf16.h>

typedef __hip_bfloat16 bf16;
typedef __bf16 bf16x8 __attribute__((ext_vector_type(8)));
typedef float f32x4 __attribute__((ext_vector_type(4)));

#define AS1 __attribute__((address_space(1)))
#define AS3 __attribute__((address_space(3)))
__device__ __forceinline__ void gl_lds16(const void* g, void* l) {
    __builtin_amdgcn_global_load_lds((const AS1 void*)g, (AS3 void*)l, 16, 0, 0);
}

__device__ __forceinline__ float fexp2(float x) {
#if __has_builtin(__builtin_amdgcn_exp2f)
    return __builtin_amdgcn_exp2f(x);
#else
    return exp2f(x);
#endif
}

__device__ __forceinline__ float bf16_lo(unsigned w) { return __uint_as_float(w << 16); }
__device__ __forceinline__ float bf16_hi(unsigned w) { return __uint_as_float(w & 0xffff0000u); }

// XCD-chunked bijective swizzle (T1/m204). Requires nwg % 8 == 0 (all our grids satisfy).
__device__ __forceinline__ int xcd_swz(int did, int nwg) {
    return (did & 7) * (nwg >> 3) + (did >> 3);
}

// 16x32 bf16 block, XOR-swizzled (rule #21 both-sides):
//   stage:  lane l <- global row (l>>2), colchunk (l&3)^((l>>3)&3)   [coalesced 64B/4 lanes]
//   read:   lane l -> elem offset (l&15)*32 + ((l>>4) ^ (((l&15)>>1)&3))*8   [conflict-free]

// ---------------------------------------------------------------- convert f32 -> bf16 (strided rows of 768)
// also optionally copies the fp32 input into xout (fuses the initial residual-stream memcpy)
__global__ __launch_bounds__(256) void cvt_f32_bf16_k(const float* __restrict__ in, bf16* __restrict__ out,
                                                      int ostride, int total, float* __restrict__ xout)
{
    int i = blockIdx.x * 256 + threadIdx.x;
    int e = i * 4;
    if (e >= total) return;
    int row = e / 768;
    int col = e - row * 768;
    const float4 f = *(const float4*)(in + e);
    bf16 o4[4];
    o4[0] = __float2bfloat16(f.x); o4[1] = __float2bfloat16(f.y);
    o4[2] = __float2bfloat16(f.z); o4[3] = __float2bfloat16(f.w);
    *(uint2*)(out + (size_t)row * ostride + col) = *(uint2*)o4;
    if (xout) *(float4*)(xout + e) = f;
}

// ---------------------------------------------------------------- weight transpose+convert: in[R][C] f32 -> out[C][R] bf16 (x scale)
__global__ void transpose_cvt_k(const float* __restrict__ in, bf16* __restrict__ out, int R, int C,
                                float scale, size_t lstride)
{
    __shared__ float t[32][33];
    const int tx = threadIdx.x, ty = threadIdx.y;
    in  += (size_t)blockIdx.z * R * C;
    out += (size_t)blockIdx.z * lstride;
    const int c0 = blockIdx.x * 32, r0 = blockIdx.y * 32;
    #pragma unroll
    for (int i = 0; i < 4; ++i)
        t[ty + i*8][tx] = in[(size_t)(r0 + ty + i*8) * C + c0 + tx];
    __syncthreads();
    #pragma unroll
    for (int i = 0; i < 4; ++i)
        out[(size_t)(c0 + ty + i*8) * R + r0 + tx] = __float2bfloat16(t[tx][ty + i*8] * scale);
}

// ---------------------------------------------------------------- GEMM: C[M,N] = A[M,K](lda) @ BT[N,K]^T, bf16 in, fp32 acc
// R10-proven structure: 128x128 tile, 4 waves, BK=32, XOR-swizzled fragment blocks, 3-buffer
// counted-vmcnt pipeline (distance 2, one raw barrier/iter, never vmcnt(0) mid-loop),
// cols-fastest XCD chunk (A slice L2-resident).
// EPI: 0 = bf16, 1 = bf16+ReLU, 4 = qkv-routed (q from A / k,v from A2; q->Cp, k->Ck, v->Cv transposed)
template<int EPI>
__global__ __launch_bounds__(256) void gemm_bt_k(const bf16* __restrict__ A, int lda,
                                                 const bf16* __restrict__ BT, int K,
                                                 void* __restrict__ Cp, int ldc,
                                                 bf16* __restrict__ Ck, bf16* __restrict__ Cv,
                                                 const bf16* __restrict__ A2)
{
    __shared__ bf16 a_sm[3][4096];
    __shared__ bf16 b_sm[3][4096];
    const int tid = threadIdx.x;
    const int lane = tid & 63;
    const int wid = tid >> 6;
    const int wr = wid >> 1, wc = wid & 1;

    const int nwg = gridDim.x * gridDim.y;
    const int did = blockIdx.x + gridDim.x * blockIdx.y;
    const int wgid = xcd_swz(did, nwg);
    const int col0 = (wgid % gridDim.y) * 128;   // cols fastest within XCD chunk -> A slice L2-resident
    const int row0 = (wgid / gridDim.y) * 128;
    const int g = lane >> 4, r16 = lane & 15;

    // qkv routing: tile's 128 cols lie inside one 768-segment (wave-uniform select)
    if (EPI == 4 && col0 >= 768) A = A2;     // q from A, k/v from A2

    // staging (coalesced, swizzle-inverse on source): lane l -> row l>>2, colchunk (l&3)^((l>>3)&3)
    const int r4 = lane >> 2;
    const int sc = (lane & 3) ^ ((lane >> 3) & 3);
    const bf16* gA[2]; const bf16* gB[2]; int loff[2];
    #pragma unroll
    for (int i = 0; i < 2; ++i) {
        const int blk = wid*2 + i;
        gA[i] = A  + (size_t)(row0 + blk*16 + r4) * lda + sc*8;
        gB[i] = BT + (size_t)(col0 + blk*16 + r4) * K   + sc*8;
        loff[i] = blk * 512;                 // wave-uniform LDS base; HW appends lane*16
    }
    // fragment read offset (elements) within a 512-elem block, swizzled
    const int foff = r16*32 + ((g ^ ((r16 >> 1) & 3)) * 8);

    f32x4 acc[4][4];
    #pragma unroll
    for (int m = 0; m < 4; ++m)
        #pragma unroll
        for (int n = 0; n < 4; ++n)
            #pragma unroll
            for (int r = 0; r < 4; ++r) acc[m][n][r] = 0.f;

    // prologue: stage tiles 0 and 1 (K is always >= 64 here)
    #pragma unroll
    for (int i = 0; i < 2; ++i) {
        gl_lds16(gA[i],      &a_sm[0][loff[i]]);
        gl_lds16(gB[i],      &b_sm[0][loff[i]]);
    }
    #pragma unroll
    for (int i = 0; i < 2; ++i) {
        gl_lds16(gA[i] + 32, &a_sm[1][loff[i]]);
        gl_lds16(gB[i] + 32, &b_sm[1][loff[i]]);
    }

    int cur = 0, pre = 2;
    for (int k0 = 0; k0 < K; k0 += 32) {
        // own tile-t loads done (4 newest = t+1's stay in flight); last iter: drain
        if (k0 + 32 < K) asm volatile("s_waitcnt vmcnt(4)" ::: "memory");
        else             asm volatile("s_waitcnt vmcnt(0)" ::: "memory");
        __builtin_amdgcn_s_barrier();        // all waves' t-loads landed; prev reads of slot 'pre' done
        if (k0 + 64 < K) {                   // stage t+2 into slot pre
            #pragma unroll
            for (int i = 0; i < 2; ++i) {
                gl_lds16(gA[i] + k0 + 64, &a_sm[pre][loff[i]]);
                gl_lds16(gB[i] + k0 + 64, &b_sm[pre][loff[i]]);
            }
        }
        bf16x8 af[4], bfr[4];
        #pragma unroll
        for (int m = 0; m < 4; ++m) af[m]  = *(const bf16x8*)&a_sm[cur][(wr*4 + m)*512 + foff];
        #pragma unroll
        for (int n = 0; n < 4; ++n) bfr[n] = *(const bf16x8*)&b_sm[cur][(wc*4 + n)*512 + foff];
        asm volatile("s_waitcnt lgkmcnt(0)" ::: "memory");   // frag reads complete before barrier arrival
        __builtin_amdgcn_s_setprio(1);
        #pragma unroll
        for (int m = 0; m < 4; ++m)
            #pragma unroll
            for (int n = 0; n < 4; ++n)
                acc[m][n] = __builtin_amdgcn_mfma_f32_16x16x32_bf16(af[m], bfr[n], acc[m][n], 0, 0, 0);
        __builtin_amdgcn_s_setprio(0);
        cur = (cur == 2) ? 0 : cur + 1;
        pre = (pre == 2) ? 0 : pre + 1;
    }

    #pragma unroll
    for (int m = 0; m < 4; ++m) {
        const int orow = row0 + wr*64 + m*16 + g*4;   // row = (lane>>4)*4 + reg
        #pragma unroll
        for (int n = 0; n < 4; ++n) {
            const int ocol = col0 + wc*64 + n*16 + r16;  // col = lane&15
            if (EPI == 4) {
                const int seg = ocol / 768;          // uniform per block (tile within one segment)
                const int ci = ocol - seg*768;
                if (seg <= 1) {
                    bf16* dst = (seg == 0) ? (bf16*)Cp : Ck;
                    #pragma unroll
                    for (int r = 0; r < 4; ++r)
                        dst[(size_t)(orow + r)*768 + ci] = __float2bfloat16(acc[m][n][r]);
                } else {                              // v: transposed [(n*8+h)*96+d][s]
                    const int nn = orow >> 10, ss = orow & 1023;
                    const int hh = ci / 96, dd = ci - hh * 96;
                    bf16 pk[4];
                    #pragma unroll
                    for (int r = 0; r < 4; ++r) pk[r] = __float2bfloat16(acc[m][n][r]);
                    *(uint2*)&Cv[(((size_t)nn*8 + hh)*96 + dd)*1024 + ss] = *(uint2*)pk;
                }
            } else {
                #pragma unroll
                for (int r = 0; r < 4; ++r) {
                    float v = acc[m][n][r];
                    if (EPI == 1) v = fmaxf(v, 0.f);
                    ((bf16*)Cp)[(size_t)(orow + r)*ldc + ocol] = __float2bfloat16(v);
                }
            }
        }
    }
}

// ---------------------------------------------------------------- flash attention, swapped-QK^T + defer-max
// 8 waves/block, 32 q-rows/wave. K/V XOR-swizzled fragment blocks, 3-buffer counted-vmcnt pipeline
// (distance 2, one raw barrier/iter). Q pre-scaled by log2(e)/sqrt(96) -> exp2 domain.
__global__ __launch_bounds__(512) void attn_k(const bf16* __restrict__ qb, const bf16* __restrict__ kb,
                                              const bf16* __restrict__ vtb, bf16* __restrict__ msgb)
{
    __shared__ bf16 kv_sm[3][12*512];       // per buf: 6 K-frag blocks + 6 V-frag blocks (512 bf16 each)
    __shared__ bf16 p_sm_all[8][32][40];
    const int tid = threadIdx.x;
    const int lane = tid & 63;
    const int w = tid >> 6;
    const int g = lane >> 4, r16 = lane & 15;

    const int nwg = gridDim.x * gridDim.y;
    const int did = blockIdx.x + gridDim.x * blockIdx.y;
    const int wgid = xcd_swz(did, nwg);
    const int qx = wgid % gridDim.x;
    const int nh = wgid / gridDim.x;
    const int n = nh >> 3, h = nh & 7;
    const int q0 = qx * 256 + w * 32;

    bf16 (*p_sm)[40] = p_sm_all[w];

    const bf16* kbase = kb  + ((size_t)n*1024)*768 + (size_t)h*96;
    const bf16* vbase = vtb + ((size_t)(n*8 + h))*96*1024;

    // Q fragments (B-operand): 2 x 16-row groups, already scaled
    bf16x8 aq[2][3];
    #pragma unroll
    for (int qh = 0; qh < 2; ++qh) {
        const size_t qoff = ((size_t)n*1024 + q0 + qh*16 + r16) * 768 + (size_t)h*96;
        #pragma unroll
        for (int c = 0; c < 3; ++c) aq[qh][c] = *(const bf16x8*)&qb[qoff + c*32 + g*8];
    }

    // staging (coalesced, swizzle-inverse): lane l -> row l>>2, colchunk (l&3)^((l>>3)&3)
    const int r4 = lane >> 2;
    const int sc = (lane & 3) ^ ((lane >> 3) & 3);
    const bf16* gsrc[2]; size_t gstep[2]; int dstoff[2];
    const int nissue = (w < 4) ? 2 : 1;
    #pragma unroll
    for (int jj = 0; jj < 2; ++jj) {
        const int issue = w + jj*8;
        if (issue < 6) {
            const int c = issue >> 1, kh = issue & 1;
            gsrc[jj]  = kbase + (size_t)(kh*16 + r4)*768 + c*32 + sc*8;
            gstep[jj] = 768;
        } else {
            gsrc[jj]  = vbase + (size_t)((issue-6)*16 + r4)*1024 + sc*8;
            gstep[jj] = 1;
        }
        dstoff[jj] = (issue < 12) ? issue * 512 : 0;
    }
    const int foff = r16*32 + ((g ^ ((r16 >> 1) & 3)) * 8);   // swizzled fragment read offset

    float m_run[2], l_run[2];
    #pragma unroll
    for (int qh = 0; qh < 2; ++qh) { m_run[qh] = -1e30f; l_run[qh] = 0.f; }
    f32x4 o[2][6];
    #pragma unroll
    for (int qg = 0; qg < 2; ++qg)
        #pragma unroll
        for (int f = 0; f < 6; ++f)
            #pragma unroll
            for (int r = 0; r < 4; ++r) o[qg][f][r] = 0.f;

    // prologue: stage tiles 0 and 1
    gl_lds16(gsrc[0], &kv_sm[0][dstoff[0]]);
    if (nissue == 2) gl_lds16(gsrc[1], &kv_sm[0][dstoff[1]]);
    gl_lds16(gsrc[0] + 32 * gstep[0], &kv_sm[1][dstoff[0]]);
    if (nissue == 2) gl_lds16(gsrc[1] + 32 * gstep[1], &kv_sm[1][dstoff[1]]);

    int cur = 0, pre = 2;
    for (int kt = 0; kt < 1024; kt += 32) {
        if (kt + 32 < 1024) {
            if (nissue == 2) asm volatile("s_waitcnt vmcnt(2)" ::: "memory");
            else             asm volatile("s_waitcnt vmcnt(1)" ::: "memory");
        } else {
            asm volatile("s_waitcnt vmcnt(0)" ::: "memory");
        }
        __builtin_amdgcn_s_barrier();
        if (kt + 64 < 1024) {                // stage t+2 into slot pre
            gl_lds16(gsrc[0] + (size_t)(kt + 64) * gstep[0], &kv_sm[pre][dstoff[0]]);
            if (nissue == 2) gl_lds16(gsrc[1] + (size_t)(kt + 64) * gstep[1], &kv_sm[pre][dstoff[1]]);
        }
        const bf16* rd = kv_sm[cur];

        // QK^T swapped: s[kh][qh], C col = q (lane&15), row = k ((lane>>4)*4+reg)
        f32x4 s[2][2];
        #pragma unroll
        for (int kh = 0; kh < 2; ++kh)
            #pragma unroll
            for (int qh = 0; qh < 2; ++qh)
                #pragma unroll
                for (int r = 0; r < 4; ++r) s[kh][qh][r] = 0.f;
        __builtin_amdgcn_s_setprio(1);
        #pragma unroll
        for (int c = 0; c < 3; ++c) {
            bf16x8 ak0 = *(const bf16x8*)&rd[(c*2 + 0)*512 + foff];
            bf16x8 ak1 = *(const bf16x8*)&rd[(c*2 + 1)*512 + foff];
            s[0][0] = __builtin_amdgcn_mfma_f32_16x16x32_bf16(ak0, aq[0][c], s[0][0], 0, 0, 0);
            s[0][1] = __builtin_amdgcn_mfma_f32_16x16x32_bf16(ak0, aq[1][c], s[0][1], 0, 0, 0);
            s[1][0] = __builtin_amdgcn_mfma_f32_16x16x32_bf16(ak1, aq[0][c], s[1][0], 0, 0, 0);
            s[1][1] = __builtin_amdgcn_mfma_f32_16x16x32_bf16(ak1, aq[1][c], s[1][1], 0, 0, 0);
        }
        __builtin_amdgcn_s_setprio(0);

        // softmax, col-layout state (q = lane&15 per qh)
        float pmv[2], gr[2];
        #pragma unroll
        for (int qh = 0; qh < 2; ++qh) {
            float pm = fmaxf(fmaxf(fmaxf(s[0][qh][0], s[0][qh][1]), fmaxf(s[0][qh][2], s[0][qh][3])),
                             fmaxf(fmaxf(s[1][qh][0], s[1][qh][1]), fmaxf(s[1][qh][2], s[1][qh][3])));
            pm = fmaxf(pm, __shfl_xor(pm, 16, 64));
            pm = fmaxf(pm, __shfl_xor(pm, 32, 64));
            pmv[qh] = pm;
            gr[qh] = pm - m_run[qh];
        }
        if (__any(fmaxf(gr[0], gr[1]) > 8.0f)) {   // rare rescale (defer-max, THR=8 in log2)
            float alpha_c[2];
            #pragma unroll
            for (int qh = 0; qh < 2; ++qh) {
                float mn = fmaxf(m_run[qh], pmv[qh]);
                alpha_c[qh] = fexp2(m_run[qh] - mn);
                m_run[qh] = mn;
                l_run[qh] *= alpha_c[qh];
            }
            #pragma unroll
            for (int qg = 0; qg < 2; ++qg)
                #pragma unroll
                for (int r = 0; r < 4; ++r) {
                    float ar = __shfl(alpha_c[qg], g*4 + r, 64);   // col->row layout transpose
                    #pragma unroll
                    for (int f = 0; f < 6; ++f) o[qg][f][r] *= ar;
                }
        }
        #pragma unroll
        for (int qh = 0; qh < 2; ++qh) {
            bf16 pk0[4], pk1[4];
            float rs = 0.f;
            #pragma unroll
            for (int r = 0; r < 4; ++r) {
                float p0 = fexp2(s[0][qh][r] - m_run[qh]);
                float p1 = fexp2(s[1][qh][r] - m_run[qh]);
                rs += p0 + p1;
                pk0[r] = __float2bfloat16(p0);
                pk1[r] = __float2bfloat16(p1);
            }
            rs += __shfl_xor(rs, 16, 64);
            rs += __shfl_xor(rs, 32, 64);
            l_run[qh] += rs;
            *(uint2*)&p_sm[qh*16 + r16][g*4]      = *(uint2*)pk0;   // P[q][k], 4 k per 8B write
            *(uint2*)&p_sm[qh*16 + r16][16 + g*4] = *(uint2*)pk1;
        }

        // PV: A = P rows(q), B = V^T rows(d)
        bf16x8 pa0 = *(const bf16x8*)&p_sm[r16][g*8];
        bf16x8 pa1 = *(const bf16x8*)&p_sm[16 + r16][g*8];
        __builtin_amdgcn_s_setprio(1);
        #pragma unroll
        for (int f = 0; f < 6; ++f) {
            bf16x8 bv = *(const bf16x8*)&rd[(6 + f)*512 + foff];
            o[0][f] = __builtin_amdgcn_mfma_f32_16x16x32_bf16(pa0, bv, o[0][f], 0, 0, 0);
            o[1][f] = __builtin_amdgcn_mfma_f32_16x16x32_bf16(pa1, bv, o[1][f], 0, 0, 0);
        }
        __builtin_amdgcn_s_setprio(0);
        asm volatile("s_waitcnt lgkmcnt(0)" ::: "memory");   // all rd/p_sm reads done before barrier arrival
        cur = (cur == 2) ? 0 : cur + 1;
        pre = (pre == 2) ? 0 : pre + 1;
    }

    // l is in col-layout; transpose via shfl for the row-layout output
    float linv[2][4];
    #pragma unroll
    for (int qg = 0; qg < 2; ++qg)
        #pragma unroll
        for (int r = 0; r < 4; ++r)
            linv[qg][r] = 1.0f / __shfl(l_run[qg], g*4 + r, 64);

    #pragma unroll
    for (int qg = 0; qg < 2; ++qg) {
        const size_t obase = ((size_t)n*1024 + q0 + qg*16 + g*4) * 768 + (size_t)h*96;
        #pragma unroll
        for (int f = 0; f < 6; ++f)
            #pragma unroll
            for (int r = 0; r < 4; ++r)
                msgb[obase + (size_t)r*768 + f*16 + r16] = __float2bfloat16(o[qg][f][r] * linv[qg][r]);
    }
}

// ---------------------------------------------------------------- LayerNorm over 768 (bf16 input), VECTORIZED
// one wave per row, 4 rows/block; lane l handles cols [8l,8l+8) (16B) and [512+4l,+4) (8B)
// MODE 1: write bf16 into concat right half (stride 1536, offset 768)
// MODE 2: x += LN(in); also write bf16 of new x into concat left half (stride 1536, offset 0)
template<int MODE>
__global__ __launch_bounds__(256) void ln_k(const bf16* __restrict__ in, const float* __restrict__ g,
                                            const float* __restrict__ b, bf16* __restrict__ outc,
                                            float* __restrict__ x)
{
    const int lane = threadIdx.x & 63;
    const int w = threadIdx.x >> 6;
    const int row = blockIdx.x * 4 + w;
    const bf16* rp = in + (size_t)row * 768;
    const int c1 = lane * 8, c2 = 512 + lane * 4;

    const uint4 u1 = *(const uint4*)&rp[c1];   // 8 bf16
    const uint2 u2 = *(const uint2*)&rp[c2];   // 4 bf16
    float f1[8], f2[4];
    f1[0] = bf16_lo(u1.x); f1[1] = bf16_hi(u1.x);
    f1[2] = bf16_lo(u1.y); f1[3] = bf16_hi(u1.y);
    f1[4] = bf16_lo(u1.z); f1[5] = bf16_hi(u1.z);
    f1[6] = bf16_lo(u1.w); f1[7] = bf16_hi(u1.w);
    f2[0] = bf16_lo(u2.x); f2[1] = bf16_hi(u2.x);
    f2[2] = bf16_lo(u2.y); f2[3] = bf16_hi(u2.y);
    float s = 0.f, sq = 0.f;
    #pragma unroll
    for (int j = 0; j < 8; ++j) { s += f1[j]; sq += f1[j]*f1[j]; }
    #pragma unroll
    for (int j = 0; j < 4; ++j) { s += f2[j]; sq += f2[j]*f2[j]; }
    #pragma unroll
    for (int off = 1; off < 64; off <<= 1) {
        s  += __shfl_xor(s,  off, 64);
        sq += __shfl_xor(sq, off, 64);
    }
    const float mu = s * (1.f/768.f);
    float var = sq * (1.f/768.f) - mu*mu;
    var = fmaxf(var, 0.f);
    const float rs = rsqrtf(var + 1e-5f);

    const float4 ga  = *(const float4*)&g[c1];
    const float4 gb4 = *(const float4*)&g[c1 + 4];
    const float4 gc  = *(const float4*)&g[c2];
    const float4 ba  = *(const float4*)&b[c1];
    const float4 bb4 = *(const float4*)&b[c1 + 4];
    const float4 bc  = *(const float4*)&b[c2];
    float y1[8], y2[4];
    y1[0] = (f1[0]-mu)*rs*ga.x + ba.x;   y1[1] = (f1[1]-mu)*rs*ga.y + ba.y;
    y1[2] = (f1[2]-mu)*rs*ga.z + ba.z;   y1[3] = (f1[3]-mu)*rs*ga.w + ba.w;
    y1[4] = (f1[4]-mu)*rs*gb4.x + bb4.x; y1[5] = (f1[5]-mu)*rs*gb4.y + bb4.y;
    y1[6] = (f1[6]-mu)*rs*gb4.z + bb4.z; y1[7] = (f1[7]-mu)*rs*gb4.w + bb4.w;
    y2[0] = (f2[0]-mu)*rs*gc.x + bc.x;   y2[1] = (f2[1]-mu)*rs*gc.y + bc.y;
    y2[2] = (f2[2]-mu)*rs*gc.z + bc.z;   y2[3] = (f2[3]-mu)*rs*gc.w + bc.w;

    if (MODE == 1) {
        bf16 o1[8], o2[4];
        #pragma unroll
        for (int j = 0; j < 8; ++j) o1[j] = __float2bfloat16(y1[j]);
        #pragma unroll
        for (int j = 0; j < 4; ++j) o2[j] = __float2bfloat16(y2[j]);
        *(uint4*)&outc[(size_t)row*1536 + 768 + c1] = *(uint4*)o1;
        *(uint2*)&outc[(size_t)row*1536 + 768 + c2] = *(uint2*)o2;
    } else {
        float* xr = x + (size_t)row * 768;
        float4 xa = *(float4*)&xr[c1];
        float4 xb = *(float4*)&xr[c1 + 4];
        float4 xc = *(float4*)&xr[c2];
        xa.x += y1[0]; xa.y += y1[1]; xa.z += y1[2]; xa.w += y1[3];
        xb.x += y1[4]; xb.y += y1[5]; xb.z += y1[6]; xb.w += y1[7];
        xc.x += y2[0]; xc.y += y2[1]; xc.z += y2[2]; xc.w += y2[3];
        *(float4*)&xr[c1]     = xa;
        *(float4*)&xr[c1 + 4] = xb;
        *(float4*)&xr[c2]     = xc;
        bf16 o1[8], o2[4];
        o1[0] = __float2bfloat16(xa.x); o1[1] = __float2bfloat16(xa.y);
        o1[2] = __float2bfloat16(xa.z); o1[3] = __float2bfloat16(xa.w);
        o1[4] = __float2bfloat16(xb.x); o1[5] = __float2bfloat16(xb.y);
        o1[6] = __float2bfloat16(xb.z); o1[7] = __float2bfloat16(xb.w);
        o2[0] = __float2bfloat16(xc.x); o2[1] = __float2bfloat16(xc.y);
        o2[2] = __float2bfloat16(xc.z); o2[3] = __float2bfloat16(xc.w);
        *(uint4*)&outc[(size_t)row*1536 + c1] = *(uint4*)o1;
        *(uint2*)&outc[(size_t)row*1536 + c2] = *(uint2*)o2;
    }
}

// ---------------------------------------------------------------- host
extern "C" void kernel_launch(void* const* d_in, const int* in_sizes, int n_in,
                              void* d_out, int out_size, void* d_ws, size_t ws_size,
                              hipStream_t stream)
{
    const float* feat0 = (const float*)d_in[0];
    const float* feat1 = (const float*)d_in[1];
    const float* Wq = (const float*)d_in[2];
    const float* Wk = (const float*)d_in[3];
    const float* Wv = (const float*)d_in[4];
    const float* Wm = (const float*)d_in[5];
    const float* W1 = (const float*)d_in[6];
    const float* W2 = (const float*)d_in[7];
    const float* g1 = (const float*)d_in[8];
    const float* b1 = (const float*)d_in[9];
    const float* g2 = (const float*)d_in[10];
    const float* b2 = (const float*)d_in[11];

    // workspace plan; RB = row capacity of activation buffers (16384 if batched self layers fit)
    bf16 *wqkvT, *wmT, *w1T, *w2T, *concat0, *concat1, *qb, *kb, *vtb, *m1b, *t0b;
    auto plan = [&](int RB) -> size_t {
        char* p = (char*)d_ws;
        auto take = [&](size_t bytes) { char* q = p; p += (bytes + 255) & ~(size_t)255; return q; };
        wqkvT = (bf16*)take((size_t)8*2304*768*2);
        wmT  = (bf16*)take((size_t)8*768*768*2);
        w1T  = (bf16*)take((size_t)8*1536*1536*2);
        w2T  = (bf16*)take((size_t)8*768*1536*2);
        concat0 = (bf16*)take((size_t)8192*1536*2);   // concat1 must follow contiguously
        concat1 = (bf16*)take((size_t)8192*1536*2);
        qb   = (bf16*)take((size_t)RB*768*2);
        kb   = (bf16*)take((size_t)RB*768*2);
        vtb  = (bf16*)take((size_t)RB*768*2);
        m1b  = (bf16*)take((size_t)RB*1536*2);
        t0b  = (bf16*)take((size_t)RB*768*2);
        return (size_t)(p - (char*)d_ws);
    };
    bool batched = plan(16384) <= ws_size;
    if (!batched) plan(8192);
    bf16* msgb = qb;  // alias: attn reads its Q region before writing msg; regions per block coincide

    float* x0 = (float*)d_out;
    float* x1 = x0 + (size_t)8192*768;

    const float s_qk = 0.14724444f;  // log2(e)/sqrt(96), folded into Wq -> QK^T lands in exp2 domain
    const dim3 tb(32, 8);
    const size_t QKV = (size_t)2304*768;
    transpose_cvt_k<<<dim3(24,24,8), tb, 0, stream>>>(Wq, wqkvT,            768, 768,  s_qk, QKV);
    transpose_cvt_k<<<dim3(24,24,8), tb, 0, stream>>>(Wk, wqkvT + 768*768,  768, 768,  1.0f, QKV);
    transpose_cvt_k<<<dim3(24,24,8), tb, 0, stream>>>(Wv, wqkvT + 1536*768, 768, 768,  1.0f, QKV);
    transpose_cvt_k<<<dim3(24,24,8), tb, 0, stream>>>(Wm, wmT, 768, 768,  1.0f, (size_t)768*768);
    transpose_cvt_k<<<dim3(48,48,8), tb, 0, stream>>>(W1, w1T, 1536, 1536, 1.0f, (size_t)1536*1536);
    transpose_cvt_k<<<dim3(24,48,8), tb, 0, stream>>>(W2, w2T, 1536, 768,  1.0f, (size_t)1536*768);

    const int total = 8192*768;
    // fused: bf16 concat-left write + fp32 residual-stream init (replaces 2x hipMemcpyAsync)
    cvt_f32_bf16_k<<<6144, 256, 0, stream>>>(feat0, concat0, 1536, total, x0);
    cvt_f32_bf16_k<<<6144, 256, 0, stream>>>(feat1, concat1, 1536, total, x1);

    // one encoder layer over M rows (M = 8192, or 16384 for batched self pairs)
    // qkv in ONE launch: q-segment reads cS, k/v-segments read cR (self: cR == cS)
    auto encode = [&](float* x, bf16* cS, const bf16* cR, int i, int M) {
        const bf16* wl = wqkvT + (size_t)i * QKV;
        const int MT = M / 128;
        gemm_bt_k<4><<<dim3(MT,18), 256, 0, stream>>>(cS, 1536, wl, 768, qb, 768, kb, vtb, cR);
        attn_k<<<dim3(4, (M/1024)*8), 512, 0, stream>>>(qb, kb, vtb, msgb);
        gemm_bt_k<0><<<dim3(MT,6),  256, 0, stream>>>(msgb, 768, wmT + (size_t)i*768*768, 768,
                                                      t0b, 768, nullptr, nullptr, nullptr);
        ln_k<1><<<M/4, 256, 0, stream>>>(t0b, g1 + i*768, b1 + i*768, cS, nullptr);
        gemm_bt_k<1><<<dim3(MT,12), 256, 0, stream>>>(cS, 1536, w1T + (size_t)i*1536*1536, 1536,
                                                      m1b, 1536, nullptr, nullptr, nullptr);
        gemm_bt_k<0><<<dim3(MT,6),  256, 0, stream>>>(m1b, 1536, w2T + (size_t)i*768*1536, 1536,
                                                      t0b, 768, nullptr, nullptr, nullptr);
        ln_k<2><<<M/4, 256, 0, stream>>>(t0b, g2 + i*768, b2 + i*768, cS, x);
    };

    for (int i = 0; i < 8; ++i) {
        if ((i & 1) == 0) {
            if (batched) {
                // feat0/feat1 self layers are independent; x0|x1 and concat0|concat1 are contiguous
                encode(x0, concat0, concat0, i, 16384);
            } else {
                encode(x0, concat0, concat0, i, 8192);
                encode(x1, concat1, concat1, i, 8192);
            }
        } else {
            encode(x0, concat0, concat1, i, 8192);
            encode(x1, concat1, concat0, i, 8192);
        }
    }
}